// Round 5
// baseline (272.897 us; speedup 1.0000x reference)
//
#include <hip/hip_runtime.h>
#include <hip/hip_bf16.h>

#define D_MODEL 2048
#define NQH 32
#define NKVH 8
#define HD 64
#define SEQ 2048
#define BATCH 2
#define MTOT (BATCH * SEQ) // 4096

typedef __attribute__((ext_vector_type(8))) short short8;
typedef __attribute__((ext_vector_type(4))) float floatx4;
typedef __attribute__((ext_vector_type(16))) float f32x16;

// Q pre-scale: (1/sqrt(64)) * log2(e)  -> softmax via exp2
#define QSCALE 0.18033688011112042f

#if __has_builtin(__builtin_amdgcn_exp2f)
#define EXP2(x) __builtin_amdgcn_exp2f(x)
#else
#define EXP2(x) exp2f(x)
#endif

static __device__ inline unsigned cvtpk(float lo, float hi) {
  unsigned r;
  asm("v_cvt_pk_bf16_f32 %0, %1, %2" : "=v"(r) : "v"(lo), "v"(hi));
  return r;
}
// a' = (a.lo, b.lo), b' = (a.hi, b.hi)
#define PLSWAP(a, b) asm("v_permlane32_swap_b32 %0, %1" : "+v"(a), "+v"(b))

// async global -> LDS, 16B per lane; lds base must be wave-uniform
__device__ inline void gload_lds16(const __hip_bfloat16* g, short* lds) {
  __builtin_amdgcn_global_load_lds(
      (const __attribute__((address_space(1))) void*)g,
      (__attribute__((address_space(3))) void*)lds, 16, 0, 0);
}

// ---------------- fp32 -> bf16 elementwise (vectorized) ----------------
__global__ __launch_bounds__(256) void convx_k(const float* __restrict__ x,
                                               __hip_bfloat16* __restrict__ xb,
                                               int n4) {
  int i = blockIdx.x * 256 + threadIdx.x;
  int stride = gridDim.x * 256;
  for (; i < n4; i += stride) {
    float4 v = reinterpret_cast<const float4*>(x)[i];
    union { __hip_bfloat16 h[4]; uint2 u; } cv;
    cv.h[0] = __float2bfloat16(v.x);
    cv.h[1] = __float2bfloat16(v.y);
    cv.h[2] = __float2bfloat16(v.z);
    cv.h[3] = __float2bfloat16(v.w);
    reinterpret_cast<uint2*>(xb)[i] = cv.u;
  }
}

// ---------------- W [K][N] fp32  ->  W^T [N][K] bf16 ----------------
__global__ __launch_bounds__(256) void transw_k(const float* __restrict__ W,
                                                __hip_bfloat16* __restrict__ Wt,
                                                int Kd, int Nd) {
  __shared__ float t[32][33];
  int n0 = blockIdx.x * 32, k0 = blockIdx.y * 32;
  int tx = threadIdx.x, ty = threadIdx.y;
#pragma unroll
  for (int j = 0; j < 32; j += 8)
    t[ty + j][tx] = W[(size_t)(k0 + ty + j) * Nd + n0 + tx];
  __syncthreads();
#pragma unroll
  for (int j = 0; j < 32; j += 8)
    Wt[(size_t)(n0 + ty + j) * Kd + k0 + tx] = __float2bfloat16(t[tx][ty + j]);
}

// ---------------- GEMM  C[m][n] = sum_k A[m][k] * Bt[n][k] ----------------
template <int MODE>
__global__ __launch_bounds__(256) void gemm_bt_k(
    const __hip_bfloat16* __restrict__ A,
    const __hip_bfloat16* __restrict__ B0,
    const __hip_bfloat16* __restrict__ B1,
    const __hip_bfloat16* __restrict__ B2,
    float* __restrict__ Cf,
    __hip_bfloat16* __restrict__ O0,
    __hip_bfloat16* __restrict__ O1,
    __hip_bfloat16* __restrict__ O2) {
  constexpr int Kd = D_MODEL;
  __shared__ short As[128 * 32];
  __shared__ short Bs[128 * 32];

  const int tid = threadIdx.x;
  const int m0 = blockIdx.y * 128;
  const int n0 = blockIdx.x * 128;

  const __hip_bfloat16* Bt;
  if (MODE == 0) {
    Bt = B0 + (size_t)n0 * Kd;
  } else {
    if (n0 < 2048) Bt = B0 + (size_t)n0 * Kd;
    else if (n0 < 2560) Bt = B1 + (size_t)(n0 - 2048) * Kd;
    else Bt = B2 + (size_t)(n0 - 2560) * Kd;
  }
  const __hip_bfloat16* Ab = A + (size_t)m0 * Kd;

  const int w = tid >> 6, l = tid & 63;
  const int wr = w >> 1, wc = w & 1;
  const int lc = l & 15, l4 = l >> 4;

  const int srow = w * 32 + (l >> 2);
  const int scol = (l & 3) * 8;
  const __hip_bfloat16* ga = Ab + (size_t)srow * Kd + scol;
  const __hip_bfloat16* gb = Bt + (size_t)srow * Kd + scol;
  short* la0 = &As[(w * 32) * 32];
  short* la1 = &As[(w * 32 + 16) * 32];
  short* lb0 = &Bs[(w * 32) * 32];
  short* lb1 = &Bs[(w * 32 + 16) * 32];

  floatx4 acc[4][4] = {};

  for (int kt = 0; kt < Kd; kt += 32) {
    gload_lds16(ga + kt, la0);
    gload_lds16(ga + (size_t)16 * Kd + kt, la1);
    gload_lds16(gb + kt, lb0);
    gload_lds16(gb + (size_t)16 * Kd + kt, lb1);
    __syncthreads();

    short8 af[4], bf[4];
#pragma unroll
    for (int mi = 0; mi < 4; ++mi)
      af[mi] = *reinterpret_cast<const short8*>(&As[(wr * 64 + mi * 16 + lc) * 32 + l4 * 8]);
#pragma unroll
    for (int ni = 0; ni < 4; ++ni)
      bf[ni] = *reinterpret_cast<const short8*>(&Bs[(wc * 64 + ni * 16 + lc) * 32 + l4 * 8]);
#pragma unroll
    for (int mi = 0; mi < 4; ++mi)
#pragma unroll
      for (int ni = 0; ni < 4; ++ni)
        acc[mi][ni] = __builtin_amdgcn_mfma_f32_16x16x32_bf16(af[mi], bf[ni], acc[mi][ni], 0, 0, 0);
    __syncthreads();
  }

#pragma unroll
  for (int mi = 0; mi < 4; ++mi)
#pragma unroll
    for (int ni = 0; ni < 4; ++ni)
#pragma unroll
      for (int i = 0; i < 4; ++i) {
        int m = m0 + wr * 64 + mi * 16 + l4 * 4 + i;
        int ncol = n0 + wc * 64 + ni * 16 + lc;
        float v = acc[mi][ni][i];
        if (MODE == 0) {
          Cf[(size_t)m * 2048 + ncol] = v;
        } else {
          int bb = m >> 11, s = m & 2047;
          if (ncol < 2048) {
            int hh = ncol >> 6, dd = ncol & 63;
            O0[(((size_t)bb * NQH + hh) * SEQ + s) * HD + dd] = __float2bfloat16(v * QSCALE);
          } else if (ncol < 2560) {
            int c2 = ncol - 2048;
            int hh = c2 >> 6, dd = c2 & 63;
            O1[(((size_t)bb * NKVH + hh) * SEQ + s) * HD + dd] = __float2bfloat16(v);
          } else {
            int c2 = ncol - 2560;
            int hh = c2 >> 6, dd = c2 & 63;
            O2[(((size_t)bb * NKVH + hh) * HD + dd) * SEQ + s] = __float2bfloat16(v);
          }
        }
      }
}

// ---------------- Flash attention: coalesced swizzled staging ------------
// 1024 blocks (4/CU). Per wave: 32 q-rows, 32x32x16 MFMA.
// LDS tiles row-major [64 rows][8 chunks of 16B]; chunk c stored at position
// c ^ ((row>>2)&7)  => fragment read (32 rows, fixed logical chunk) covers
// all 32 bank-quads bijectively (conflict-free); staging source permutes the
// chunk within each 128B row (8-lane groups stay fully coalesced).
// S^T = mfma(K,Q) -> v_exp -> cvt_pk -> permlane32_swap -> PV. No P in LDS.
__global__ __launch_bounds__(256, 4) void attn_k(const __hip_bfloat16* __restrict__ Qb,
                                                 const __hip_bfloat16* __restrict__ Kb,
                                                 const __hip_bfloat16* __restrict__ Vtb,
                                                 __hip_bfloat16* __restrict__ Ao) {
  // bytes: [0,8K)=K buf0, [8K,16K)=V buf0, [16K,24K)=K buf1, [24K,32K)=V buf1
  __shared__ short SB[16384];
  __shared__ float Ls[4][32];

  const int bid = blockIdx.x;
  // 1024 blocks: 128/XCD = 2 KV-groups of 64 (4 h x 16 qt)
  const int xcd = bid & 7, j = bid >> 3;
  const int g = xcd * 2 + (j >> 6), wv = j & 63;
  const int b = g >> 3, kh = g & 7;
  const int h = kh * 4 + (wv >> 4), qt = wv & 15;

  const int tid = threadIdx.x, w = tid >> 6, l = tid & 63;
  const int q5 = l & 31, hl = l >> 5;

  const __hip_bfloat16* Qp = Qb + (((size_t)b * NQH + h) * SEQ + qt * 128 + w * 32) * HD;
  const __hip_bfloat16* Kp = Kb + ((size_t)b * NKVH + kh) * SEQ * HD;
  const __hip_bfloat16* Vp = Vtb + ((size_t)b * NKVH + kh) * HD * SEQ;

  // hoisted Q B-frags: col q = q5, d = ks*16 + hl*8 + e
  short8 qf[4];
#pragma unroll
  for (int ks = 0; ks < 4; ++ks)
    qf[ks] = *reinterpret_cast<const short8*>(Qp + (size_t)q5 * HD + ks * 16 + hl * 8);

  f32x16 acc0 = {}, acc1 = {};
  float lsum = 0.f;

  // ---- staging geometry: wave w stages row-groups g0=2w, g1=2w+1 ----
  const int g0 = 2 * w, g1 = 2 * w + 1;
  const int r0 = g0 * 8 + (l >> 3), r1 = g1 * 8 + (l >> 3);
  const int cc0 = (l & 7) ^ ((r0 >> 2) & 7);
  const int cc1 = (l & 7) ^ ((r1 >> 2) & 7);
  const __hip_bfloat16* sK0 = Kp + (size_t)r0 * HD + cc0 * 8;
  const __hip_bfloat16* sK1 = Kp + (size_t)r1 * HD + cc1 * 8;
  const __hip_bfloat16* sV0 = Vp + (size_t)r0 * SEQ + cc0 * 8;
  const __hip_bfloat16* sV1 = Vp + (size_t)r1 * SEQ + cc1 * 8;

#define STAGE(B)                                     \
  do {                                               \
    gload_lds16(sK0, &SB[(B) + g0 * 512]);           \
    gload_lds16(sK1, &SB[(B) + g1 * 512]);           \
    gload_lds16(sV0, &SB[(B) + 4096 + g0 * 512]);    \
    gload_lds16(sV1, &SB[(B) + 4096 + g1 * 512]);    \
    sK0 += 64 * HD; sK1 += 64 * HD; sV0 += 64; sV1 += 64; \
  } while (0)

  // loop-invariant fragment read offsets (shorts): row q5, logical chunk j*2+hl
  const int sw = (q5 >> 2) & 7;
  int fo[4];
#pragma unroll
  for (int jj = 0; jj < 4; ++jj)
    fo[jj] = q5 * 64 + (((jj * 2 + hl) ^ sw) * 8);

  // prologue: tile 0 -> buf 0
  STAGE(0);
  __syncthreads();

#define BODY(KB, RB, SBF)                                                       \
  do {                                                                          \
    if ((KB) + 1 < SEQ / 64) STAGE(SBF);                                        \
    short8 kf0[4], kf1[4];                                                      \
    _Pragma("unroll") for (int ks = 0; ks < 4; ++ks) {                          \
      kf0[ks] = *reinterpret_cast<const short8*>(&SB[(RB) + fo[ks]]);           \
      kf1[ks] = *reinterpret_cast<const short8*>(&SB[(RB) + fo[ks] + 2048]);    \
    }                                                                           \
    f32x16 st0 = {}, st1 = {};                                                  \
    __builtin_amdgcn_s_setprio(1);                                              \
    _Pragma("unroll") for (int ks = 0; ks < 4; ++ks) {                          \
      st0 = __builtin_amdgcn_mfma_f32_32x32x16_bf16(kf0[ks], qf[ks], st0, 0, 0, 0); \
      st1 = __builtin_amdgcn_mfma_f32_32x32x16_bf16(kf1[ks], qf[ks], st1, 0, 0, 0); \
    }                                                                           \
    __builtin_amdgcn_s_setprio(0);                                              \
    float ps = 0.f;                                                             \
    unsigned u0[8], u1[8];                                                      \
    _Pragma("unroll") for (int jj = 0; jj < 8; ++jj) {                          \
      float e0 = EXP2(st0[2 * jj]), e1 = EXP2(st0[2 * jj + 1]);                 \
      float f0 = EXP2(st1[2 * jj]), f1 = EXP2(st1[2 * jj + 1]);                 \
      ps += (e0 + e1) + (f0 + f1);                                              \
      u0[jj] = cvtpk(e0, e1);                                                   \
      u1[jj] = cvtpk(f0, f1);                                                   \
    }                                                                           \
    lsum += ps;                                                                 \
    short8 vf0[4], vf1[4];                                                      \
    _Pragma("unroll") for (int t = 0; t < 4; ++t) {                             \
      vf0[t] = *reinterpret_cast<const short8*>(&SB[(RB) + fo[t] + 4096]);      \
      vf1[t] = *reinterpret_cast<const short8*>(&SB[(RB) + fo[t] + 6144]);      \
    }                                                                           \
    PLSWAP(u0[0], u0[2]); PLSWAP(u0[1], u0[3]);                                 \
    PLSWAP(u0[4], u0[6]); PLSWAP(u0[5], u0[7]);                                 \
    PLSWAP(u1[0], u1[2]); PLSWAP(u1[1], u1[3]);                                 \
    PLSWAP(u1[4], u1[6]); PLSWAP(u1[5], u1[7]);                                 \
    __builtin_amdgcn_s_setprio(1);                                              \
    _Pragma("unroll") for (int t = 0; t < 4; ++t) {                             \
      union { unsigned w4[4]; short8 s8; } pa;                                  \
      pa.w4[0] = (t >> 1 ? u1 : u0)[(t & 1) * 4 + 0];                           \
      pa.w4[1] = (t >> 1 ? u1 : u0)[(t & 1) * 4 + 1];                           \
      pa.w4[2] = (t >> 1 ? u1 : u0)[(t & 1) * 4 + 2];                           \
      pa.w4[3] = (t >> 1 ? u1 : u0)[(t & 1) * 4 + 3];                           \
      acc0 = __builtin_amdgcn_mfma_f32_32x32x16_bf16(pa.s8, vf0[t], acc0, 0, 0, 0); \
      acc1 = __builtin_amdgcn_mfma_f32_32x32x16_bf16(pa.s8, vf1[t], acc1, 0, 0, 0); \
    }                                                                           \
    __builtin_amdgcn_s_setprio(0);                                              \
    __syncthreads();                                                            \
  } while (0)

  for (int kb = 0; kb < SEQ / 64; kb += 2) {
    BODY(kb, 0, 8192);
    BODY(kb + 1, 8192, 0);
  }
#undef BODY
#undef STAGE

  // complete row sums (other k-half lane) and broadcast via per-wave LDS
  {
    float v = lsum;
    v += __shfl_xor(v, 32);
    if (l < 32) Ls[w][l] = v;
  }
  __syncthreads();

  const size_t obase = (size_t)b * SEQ + qt * 128 + w * 32;
  float inv[16];
#pragma unroll
  for (int r = 0; r < 16; ++r)
    inv[r] = 1.0f / Ls[w][(r & 3) + 8 * (r >> 2) + 4 * hl];
#pragma unroll
  for (int r = 0; r < 16; ++r) {
    int q = (r & 3) + 8 * (r >> 2) + 4 * hl;
    Ao[(obase + q) * D_MODEL + h * HD + q5] = __float2bfloat16(acc0[r] * inv[r]);
    Ao[(obase + q) * D_MODEL + h * HD + 32 + q5] = __float2bfloat16(acc1[r] * inv[r]);
  }
}

// ---------------- host ----------------
extern "C" void kernel_launch(void* const* d_in, const int* in_sizes, int n_in,
                              void* d_out, int out_size, void* d_ws, size_t ws_size,
                              hipStream_t stream) {
  const float* x  = (const float*)d_in[0];
  const float* Wq = (const float*)d_in[1];
  const float* Wk = (const float*)d_in[2];
  const float* Wv = (const float*)d_in[3];
  const float* Wo = (const float*)d_in[4];
  float* out = (float*)d_out;

  __hip_bfloat16* p = (__hip_bfloat16*)d_ws;
  __hip_bfloat16* xb  = p;
  __hip_bfloat16* Wqt = xb  + (size_t)MTOT * D_MODEL;
  __hip_bfloat16* Wkt = Wqt + (size_t)D_MODEL * D_MODEL;
  __hip_bfloat16* Wvt = Wkt + (size_t)512 * D_MODEL;
  __hip_bfloat16* Wot = Wvt + (size_t)512 * D_MODEL;
  __hip_bfloat16* Qb  = Wot + (size_t)D_MODEL * D_MODEL;
  __hip_bfloat16* Kb  = Qb  + (size_t)MTOT * D_MODEL;
  __hip_bfloat16* Vtb = Kb  + (size_t)BATCH * NKVH * SEQ * HD;
  __hip_bfloat16* Ab  = Vtb + (size_t)BATCH * NKVH * SEQ * HD;

  convx_k<<<2048, 256, 0, stream>>>(x, xb, MTOT * D_MODEL / 4);
  transw_k<<<dim3(D_MODEL / 32, D_MODEL / 32), dim3(32, 8), 0, stream>>>(Wq, Wqt, D_MODEL, D_MODEL);
  transw_k<<<dim3(512 / 32, D_MODEL / 32), dim3(32, 8), 0, stream>>>(Wk, Wkt, D_MODEL, 512);
  transw_k<<<dim3(512 / 32, D_MODEL / 32), dim3(32, 8), 0, stream>>>(Wv, Wvt, D_MODEL, 512);
  transw_k<<<dim3(D_MODEL / 32, D_MODEL / 32), dim3(32, 8), 0, stream>>>(Wo, Wot, D_MODEL, D_MODEL);

  // fused QKV projection: N = 2048 (Q) + 512 (K) + 512 (V) = 3072
  gemm_bt_k<1><<<dim3(24, MTOT / 128), 256, 0, stream>>>(xb, Wqt, Wkt, Wvt,
                                                         nullptr, Qb, Kb, Vtb);
  attn_k<<<dim3(1024), 256, 0, stream>>>(Qb, Kb, Vtb, Ab);
  // output projection -> fp32
  gemm_bt_k<0><<<dim3(D_MODEL / 128, MTOT / 128), 256, 0, stream>>>(Ab, Wot, nullptr, nullptr,
                                                                    out, nullptr, nullptr, nullptr);
}

// Round 6
// 232.001 us; speedup vs baseline: 1.1763x; 1.1763x over previous
//
#include <hip/hip_runtime.h>
#include <hip/hip_bf16.h>

#define D_MODEL 2048
#define NQH 32
#define NKVH 8
#define HD 64
#define SEQ 2048
#define BATCH 2
#define MTOT (BATCH * SEQ) // 4096

typedef __attribute__((ext_vector_type(8))) short short8;
typedef __attribute__((ext_vector_type(4))) float floatx4;
typedef __attribute__((ext_vector_type(16))) float f32x16;

// Q pre-scale: (1/sqrt(64)) * log2(e)  -> softmax via exp2
#define QSCALE 0.18033688011112042f

#if __has_builtin(__builtin_amdgcn_exp2f)
#define EXP2(x) __builtin_amdgcn_exp2f(x)
#else
#define EXP2(x) exp2f(x)
#endif

static __device__ inline unsigned cvtpk(float lo, float hi) {
  unsigned r;
  asm("v_cvt_pk_bf16_f32 %0, %1, %2" : "=v"(r) : "v"(lo), "v"(hi));
  return r;
}
// a' = (a.lo, b.lo), b' = (a.hi, b.hi)
#define PLSWAP(a, b) asm("v_permlane32_swap_b32 %0, %1" : "+v"(a), "+v"(b))

// async global -> LDS, 16B per lane; lds base must be wave-uniform
__device__ inline void gload_lds16(const __hip_bfloat16* g, short* lds) {
  __builtin_amdgcn_global_load_lds(
      (const __attribute__((address_space(1))) void*)g,
      (__attribute__((address_space(3))) void*)lds, 16, 0, 0);
}

// ---------------- fp32 -> bf16 elementwise (vectorized) ----------------
__global__ __launch_bounds__(256) void convx_k(const float* __restrict__ x,
                                               __hip_bfloat16* __restrict__ xb,
                                               int n4) {
  int i = blockIdx.x * 256 + threadIdx.x;
  int stride = gridDim.x * 256;
  for (; i < n4; i += stride) {
    float4 v = reinterpret_cast<const float4*>(x)[i];
    union { __hip_bfloat16 h[4]; uint2 u; } cv;
    cv.h[0] = __float2bfloat16(v.x);
    cv.h[1] = __float2bfloat16(v.y);
    cv.h[2] = __float2bfloat16(v.z);
    cv.h[3] = __float2bfloat16(v.w);
    reinterpret_cast<uint2*>(xb)[i] = cv.u;
  }
}

// ---------------- W [K][N] fp32  ->  W^T [N][K] bf16 ----------------
__global__ __launch_bounds__(256) void transw_k(const float* __restrict__ W,
                                                __hip_bfloat16* __restrict__ Wt,
                                                int Kd, int Nd) {
  __shared__ float t[32][33];
  int n0 = blockIdx.x * 32, k0 = blockIdx.y * 32;
  int tx = threadIdx.x, ty = threadIdx.y;
#pragma unroll
  for (int j = 0; j < 32; j += 8)
    t[ty + j][tx] = W[(size_t)(k0 + ty + j) * Nd + n0 + tx];
  __syncthreads();
#pragma unroll
  for (int j = 0; j < 32; j += 8)
    Wt[(size_t)(n0 + ty + j) * Kd + k0 + tx] = __float2bfloat16(t[tx][ty + j]);
}

// ---------------- GEMM  C[m][n] = sum_k A[m][k] * Bt[n][k] ----------------
template <int MODE>
__global__ __launch_bounds__(256) void gemm_bt_k(
    const __hip_bfloat16* __restrict__ A,
    const __hip_bfloat16* __restrict__ B0,
    const __hip_bfloat16* __restrict__ B1,
    const __hip_bfloat16* __restrict__ B2,
    float* __restrict__ Cf,
    __hip_bfloat16* __restrict__ O0,
    __hip_bfloat16* __restrict__ O1,
    __hip_bfloat16* __restrict__ O2) {
  constexpr int Kd = D_MODEL;
  __shared__ short As[128 * 32];
  __shared__ short Bs[128 * 32];

  const int tid = threadIdx.x;
  const int m0 = blockIdx.y * 128;
  const int n0 = blockIdx.x * 128;

  const __hip_bfloat16* Bt;
  if (MODE == 0) {
    Bt = B0 + (size_t)n0 * Kd;
  } else {
    if (n0 < 2048) Bt = B0 + (size_t)n0 * Kd;
    else if (n0 < 2560) Bt = B1 + (size_t)(n0 - 2048) * Kd;
    else Bt = B2 + (size_t)(n0 - 2560) * Kd;
  }
  const __hip_bfloat16* Ab = A + (size_t)m0 * Kd;

  const int w = tid >> 6, l = tid & 63;
  const int wr = w >> 1, wc = w & 1;
  const int lc = l & 15, l4 = l >> 4;

  const int srow = w * 32 + (l >> 2);
  const int scol = (l & 3) * 8;
  const __hip_bfloat16* ga = Ab + (size_t)srow * Kd + scol;
  const __hip_bfloat16* gb = Bt + (size_t)srow * Kd + scol;
  short* la0 = &As[(w * 32) * 32];
  short* la1 = &As[(w * 32 + 16) * 32];
  short* lb0 = &Bs[(w * 32) * 32];
  short* lb1 = &Bs[(w * 32 + 16) * 32];

  floatx4 acc[4][4] = {};

  for (int kt = 0; kt < Kd; kt += 32) {
    gload_lds16(ga + kt, la0);
    gload_lds16(ga + (size_t)16 * Kd + kt, la1);
    gload_lds16(gb + kt, lb0);
    gload_lds16(gb + (size_t)16 * Kd + kt, lb1);
    __syncthreads();

    short8 af[4], bf[4];
#pragma unroll
    for (int mi = 0; mi < 4; ++mi)
      af[mi] = *reinterpret_cast<const short8*>(&As[(wr * 64 + mi * 16 + lc) * 32 + l4 * 8]);
#pragma unroll
    for (int ni = 0; ni < 4; ++ni)
      bf[ni] = *reinterpret_cast<const short8*>(&Bs[(wc * 64 + ni * 16 + lc) * 32 + l4 * 8]);
#pragma unroll
    for (int mi = 0; mi < 4; ++mi)
#pragma unroll
      for (int ni = 0; ni < 4; ++ni)
        acc[mi][ni] = __builtin_amdgcn_mfma_f32_16x16x32_bf16(af[mi], bf[ni], acc[mi][ni], 0, 0, 0);
    __syncthreads();
  }

#pragma unroll
  for (int mi = 0; mi < 4; ++mi)
#pragma unroll
    for (int ni = 0; ni < 4; ++ni)
#pragma unroll
      for (int i = 0; i < 4; ++i) {
        int m = m0 + wr * 64 + mi * 16 + l4 * 4 + i;
        int ncol = n0 + wc * 64 + ni * 16 + lc;
        float v = acc[mi][ni][i];
        if (MODE == 0) {
          Cf[(size_t)m * 2048 + ncol] = v;
        } else {
          int bb = m >> 11, s = m & 2047;
          if (ncol < 2048) {
            int hh = ncol >> 6, dd = ncol & 63;
            O0[(((size_t)bb * NQH + hh) * SEQ + s) * HD + dd] = __float2bfloat16(v * QSCALE);
          } else if (ncol < 2560) {
            int c2 = ncol - 2048;
            int hh = c2 >> 6, dd = c2 & 63;
            O1[(((size_t)bb * NKVH + hh) * SEQ + s) * HD + dd] = __float2bfloat16(v);
          } else {
            int c2 = ncol - 2560;
            int hh = c2 >> 6, dd = c2 & 63;
            O2[(((size_t)bb * NKVH + hh) * HD + dd) * SEQ + s] = __float2bfloat16(v);
          }
        }
      }
}

// ---------------- Flash attention: coalesced staging, compact body ------
// 1024 blocks (4/CU). Per wave: 32 q-rows, 32x32x16 MFMA.
// LDS tiles [64 rows][8 chunks of 16B], phys_chunk = logical ^ (row&7):
//  - staging: lane l stages row 16w+(l>>3), src chunk (l&7)^((l>>3)&7);
//    one DMA covers 8 fully-used cache lines (K: 1KB contiguous), LDS dest
//    linear (rule: swizzle source + reads, never the DMA dest).
//  - fragment reads: offset q5*64 + ((c ^ (q5&7))*8); XOR term uniform over
//    lanes -> balanced banks; rows+32 share the same offset +2048.
// S^T = mfma(K,Q) -> v_exp -> cvt_pk -> permlane32_swap -> PV. No P in LDS.
__global__ __launch_bounds__(256, 4) void attn_k(const __hip_bfloat16* __restrict__ Qb,
                                                 const __hip_bfloat16* __restrict__ Kb,
                                                 const __hip_bfloat16* __restrict__ Vtb,
                                                 __hip_bfloat16* __restrict__ Ao) {
  __shared__ short Ks[2][64 * 64];
  __shared__ short Vs[2][64 * 64];
  __shared__ float Ls[4][32];

  const int bid = blockIdx.x;
  // 1024 blocks: 128/XCD = 2 KV-groups of 64 (4 h x 16 qt)
  const int xcd = bid & 7, j = bid >> 3;
  const int g = xcd * 2 + (j >> 6), wv = j & 63;
  const int b = g >> 3, kh = g & 7;
  const int h = kh * 4 + (wv >> 4), qt = wv & 15;

  const int tid = threadIdx.x, w = tid >> 6, l = tid & 63;
  const int q5 = l & 31, hl = l >> 5;

  const __hip_bfloat16* Qp = Qb + (((size_t)b * NQH + h) * SEQ + qt * 128 + w * 32) * HD;
  const __hip_bfloat16* Kp = Kb + ((size_t)b * NKVH + kh) * SEQ * HD;
  const __hip_bfloat16* Vp = Vtb + ((size_t)b * NKVH + kh) * HD * SEQ;

  // hoisted Q B-frags: col q = q5, d = ks*16 + hl*8 + e
  short8 qf[4];
#pragma unroll
  for (int ks = 0; ks < 4; ++ks)
    qf[ks] = *reinterpret_cast<const short8*>(Qp + (size_t)q5 * HD + ks * 16 + hl * 8);

  f32x16 acc0 = {}, acc1 = {};
  float lsum = 0.f;

  // coalesced swizzled staging
  const int rg = l >> 3;
  const int cc = (l & 7) ^ (rg & 7); // same for both row-groups (base % 8 == 0)
  const __hip_bfloat16* sK = Kp + (size_t)(16 * w + rg) * HD + cc * 8;
  const __hip_bfloat16* sV = Vp + (size_t)(16 * w + rg) * SEQ + cc * 8;

  // fragment read offsets (shorts): row q5, logical chunk jj*2+hl
  int fo[4];
#pragma unroll
  for (int jj = 0; jj < 4; ++jj)
    fo[jj] = q5 * 64 + (((jj * 2 + hl) ^ (q5 & 7)) * 8);

  // prologue: stage tile 0 into buf 0
  gload_lds16(sK, &Ks[0][1024 * w]);
  gload_lds16(sK + 8 * HD, &Ks[0][1024 * w + 512]);
  gload_lds16(sV, &Vs[0][1024 * w]);
  gload_lds16(sV + 8 * (size_t)SEQ, &Vs[0][1024 * w + 512]);
  sK += 64 * HD;
  sV += 64;
  __syncthreads();

  for (int kb = 0; kb < SEQ / 64; ++kb) {
    const short* Kt = Ks[kb & 1];
    const short* Vt = Vs[kb & 1];

    // prefetch next tile (issued first; completion enforced by the
    // vmcnt(0) the compiler emits for the end-of-iter __syncthreads)
    if (kb + 1 < SEQ / 64) {
      short* Kn = Ks[(kb & 1) ^ 1];
      short* Vn = Vs[(kb & 1) ^ 1];
      gload_lds16(sK, &Kn[1024 * w]);
      gload_lds16(sK + 8 * HD, &Kn[1024 * w + 512]);
      gload_lds16(sV, &Vn[1024 * w]);
      gload_lds16(sV + 8 * (size_t)SEQ, &Vn[1024 * w + 512]);
      sK += 64 * HD;
      sV += 64;
    }

    // ---- QK^T: S^T[k][q] = mfma(K, Q) ----
    short8 kf0[4], kf1[4];
#pragma unroll
    for (int ks = 0; ks < 4; ++ks) {
      kf0[ks] = *reinterpret_cast<const short8*>(&Kt[fo[ks]]);
      kf1[ks] = *reinterpret_cast<const short8*>(&Kt[fo[ks] + 2048]);
    }
    f32x16 st0 = {}, st1 = {};
    __builtin_amdgcn_s_setprio(1);
#pragma unroll
    for (int ks = 0; ks < 4; ++ks) {
      st0 = __builtin_amdgcn_mfma_f32_32x32x16_bf16(kf0[ks], qf[ks], st0, 0, 0, 0);
      st1 = __builtin_amdgcn_mfma_f32_32x32x16_bf16(kf1[ks], qf[ks], st1, 0, 0, 0);
    }
    __builtin_amdgcn_s_setprio(0);

    // ---- softmax: P = exp2(S'); partial row-sum; pack to bf16 ----
    float ps = 0.f;
    unsigned u0[8], u1[8];
#pragma unroll
    for (int jj = 0; jj < 8; ++jj) {
      float e0 = EXP2(st0[2 * jj]), e1 = EXP2(st0[2 * jj + 1]);
      float f0 = EXP2(st1[2 * jj]), f1 = EXP2(st1[2 * jj + 1]);
      ps += (e0 + e1) + (f0 + f1);
      u0[jj] = cvtpk(e0, e1);
      u1[jj] = cvtpk(f0, f1);
    }
    lsum += ps;

    // V B-frags; latency hidden under the permlane swaps
    short8 vf0[4], vf1[4];
#pragma unroll
    for (int t = 0; t < 4; ++t) {
      vf0[t] = *reinterpret_cast<const short8*>(&Vt[fo[t]]);
      vf1[t] = *reinterpret_cast<const short8*>(&Vt[fo[t] + 2048]);
    }

    // redistribute P^T -> A-frag k-octets
    PLSWAP(u0[0], u0[2]); PLSWAP(u0[1], u0[3]);
    PLSWAP(u0[4], u0[6]); PLSWAP(u0[5], u0[7]);
    PLSWAP(u1[0], u1[2]); PLSWAP(u1[1], u1[3]);
    PLSWAP(u1[4], u1[6]); PLSWAP(u1[5], u1[7]);

    // ---- PV ----
    __builtin_amdgcn_s_setprio(1);
#pragma unroll
    for (int t = 0; t < 4; ++t) {
      union { unsigned w4[4]; short8 s8; } pa;
      pa.w4[0] = (t >> 1 ? u1 : u0)[(t & 1) * 4 + 0];
      pa.w4[1] = (t >> 1 ? u1 : u0)[(t & 1) * 4 + 1];
      pa.w4[2] = (t >> 1 ? u1 : u0)[(t & 1) * 4 + 2];
      pa.w4[3] = (t >> 1 ? u1 : u0)[(t & 1) * 4 + 3];
      acc0 = __builtin_amdgcn_mfma_f32_32x32x16_bf16(pa.s8, vf0[t], acc0, 0, 0, 0);
      acc1 = __builtin_amdgcn_mfma_f32_32x32x16_bf16(pa.s8, vf1[t], acc1, 0, 0, 0);
    }
    __builtin_amdgcn_s_setprio(0);
    __syncthreads();
  }

  // complete row sums (other k-half lane) and broadcast via per-wave LDS
  {
    float v = lsum;
    v += __shfl_xor(v, 32);
    if (l < 32) Ls[w][l] = v;
  }
  __syncthreads();

  const size_t obase = (size_t)b * SEQ + qt * 128 + w * 32;
  float inv[16];
#pragma unroll
  for (int r = 0; r < 16; ++r)
    inv[r] = 1.0f / Ls[w][(r & 3) + 8 * (r >> 2) + 4 * hl];
#pragma unroll
  for (int r = 0; r < 16; ++r) {
    int q = (r & 3) + 8 * (r >> 2) + 4 * hl;
    Ao[(obase + q) * D_MODEL + h * HD + q5] = __float2bfloat16(acc0[r] * inv[r]);
    Ao[(obase + q) * D_MODEL + h * HD + 32 + q5] = __float2bfloat16(acc1[r] * inv[r]);
  }
}

// ---------------- host ----------------
extern "C" void kernel_launch(void* const* d_in, const int* in_sizes, int n_in,
                              void* d_out, int out_size, void* d_ws, size_t ws_size,
                              hipStream_t stream) {
  const float* x  = (const float*)d_in[0];
  const float* Wq = (const float*)d_in[1];
  const float* Wk = (const float*)d_in[2];
  const float* Wv = (const float*)d_in[3];
  const float* Wo = (const float*)d_in[4];
  float* out = (float*)d_out;

  __hip_bfloat16* p = (__hip_bfloat16*)d_ws;
  __hip_bfloat16* xb  = p;
  __hip_bfloat16* Wqt = xb  + (size_t)MTOT * D_MODEL;
  __hip_bfloat16* Wkt = Wqt + (size_t)D_MODEL * D_MODEL;
  __hip_bfloat16* Wvt = Wkt + (size_t)512 * D_MODEL;
  __hip_bfloat16* Wot = Wvt + (size_t)512 * D_MODEL;
  __hip_bfloat16* Qb  = Wot + (size_t)D_MODEL * D_MODEL;
  __hip_bfloat16* Kb  = Qb  + (size_t)MTOT * D_MODEL;
  __hip_bfloat16* Vtb = Kb  + (size_t)BATCH * NKVH * SEQ * HD;
  __hip_bfloat16* Ab  = Vtb + (size_t)BATCH * NKVH * SEQ * HD;

  convx_k<<<2048, 256, 0, stream>>>(x, xb, MTOT * D_MODEL / 4);
  transw_k<<<dim3(D_MODEL / 32, D_MODEL / 32), dim3(32, 8), 0, stream>>>(Wq, Wqt, D_MODEL, D_MODEL);
  transw_k<<<dim3(512 / 32, D_MODEL / 32), dim3(32, 8), 0, stream>>>(Wk, Wkt, D_MODEL, 512);
  transw_k<<<dim3(512 / 32, D_MODEL / 32), dim3(32, 8), 0, stream>>>(Wv, Wvt, D_MODEL, 512);
  transw_k<<<dim3(D_MODEL / 32, D_MODEL / 32), dim3(32, 8), 0, stream>>>(Wo, Wot, D_MODEL, D_MODEL);

  // fused QKV projection: N = 2048 (Q) + 512 (K) + 512 (V) = 3072
  gemm_bt_k<1><<<dim3(24, MTOT / 128), 256, 0, stream>>>(xb, Wqt, Wkt, Wvt,
                                                         nullptr, Qb, Kb, Vtb);
  attn_k<<<dim3(1024), 256, 0, stream>>>(Qb, Kb, Vtb, Ab);
  // output projection -> fp32
  gemm_bt_k<0><<<dim3(D_MODEL / 128, MTOT / 128), 256, 0, stream>>>(Ab, Wot, nullptr, nullptr,
                                                                    out, nullptr, nullptr, nullptr);
}